// Round 2
// 360.910 us; speedup vs baseline: 1.0189x; 1.0189x over previous
//
#include <hip/hip_runtime.h>

// SLAM layer, fused: h = relu(x_aux@W1+b1); S = h@W2+b2; out[t] = x_main[-1,t,0] @ S[:,t,:]
// N,T,M,A,D = 4,1024,128,64,128.
// v2r: identical to v2 (round-1 bench was an infra failure; resubmitting for measurement).
//     TPB=4 t-values per block (grid 256 = 1 block/CU, single round).
//     W1T/W2T staged ONCE per block with coalesced reads + b64 LDS writes (<=4-way conflict,
//     was 16-way scalar b16). 2 barriers per t-iter; Xa/A register-prefetched one iter ahead.

#define TT 1024
#define MM 128
#define AA 64
#define DD 128
#define TPB 4

typedef float  f32x4  __attribute__((ext_vector_type(4)));
typedef __bf16 bf16x8 __attribute__((ext_vector_type(8)));
typedef __bf16 bf16x4 __attribute__((ext_vector_type(4)));

// LDS row strides (elements): 64-wide mats padded to 72 (144 B), 128-wide padded to 136 (272 B).
// Frag reads are 16 B aligned; 16-lane row-step reads are 2-way max (verified layout, unchanged).

__global__ __launch_bounds__(512, 1)
void slam_fused2(const float* __restrict__ xm, const float* __restrict__ xa,
                 const float* __restrict__ W1, const float* __restrict__ b1,
                 const float* __restrict__ W2, const float* __restrict__ b2,
                 float* __restrict__ out)
{
    __shared__ __bf16 ldsW1T[ 9216];   // [d=128][72]  (a<64 valid)  - resident all iters
    __shared__ __bf16 ldsXa [ 9216];   // [m=128][72]  (a<64 valid)  - rewritten per iter
    __shared__ __bf16 ldsW2T[17408];   // [k=128][136] (d<128 valid) - resident all iters
    __shared__ __bf16 ldsH  [17408];   // [m=128][136]
    __shared__ __bf16 ldsS  [17408];   // ST[k=128][136] (col j)
    __shared__ float  ldsB1[128];
    __shared__ float  ldsB2[128];
    // total 142336 B -> 1 block/CU

    const int t0   = blockIdx.x * TPB;
    const int tid  = threadIdx.x;
    const int lane = tid & 63;
    const int wv   = tid >> 6;       // 0..7
    const int n    = lane & 15;      // MFMA col index within tile
    const int q    = lane >> 4;      // quad 0..3

    // ---- prologue: issue A(t0) and Xa(t0) global loads ----
    const float* abase = xm + (size_t)3 * TT * MM * MM;
    f32x4 apre[8];
    {
        const float* arow = abase + ((size_t)t0 * MM + wv * 16 + n) * MM;
#pragma unroll
        for (int ks = 0; ks < 4; ++ks) {
            apre[2 * ks]     = *(const f32x4*)(arow + ks * 32 + q * 8);
            apre[2 * ks + 1] = *(const f32x4*)(arow + ks * 32 + q * 8 + 4);
        }
    }
    const int xrow = tid >> 4;        // 0..31 (row base within 32-row group)
    const int xc   = (tid & 15) * 4;  // a-column (x4)
    f32x4 xpre[4];
#pragma unroll
    for (int p = 0; p < 4; ++p)
        xpre[p] = *(const f32x4*)(xa + ((size_t)(p * 32 + xrow) * TT + t0) * AA + xc);

    // ---- stage W1T: [d][a] <- W1[a][d]; lanes step d (coalesced 4B reads, b64 writes, <=4-way) ----
#pragma unroll
    for (int p = 0; p < 4; ++p) {
        int ti = p * 512 + tid;
        int d  = ti & 127;
        int aq = ti >> 7;             // 0..15
        bf16x4 pk;
#pragma unroll
        for (int r = 0; r < 4; ++r)
            pk[r] = (__bf16)W1[(size_t)(4 * aq + r) * DD + d];
        *(bf16x4*)(ldsW1T + d * 72 + aq * 4) = pk;
    }
    // ---- stage W2T: [k][d] <- W2[d][k]; lanes step k ----
#pragma unroll
    for (int p = 0; p < 8; ++p) {
        int ti = p * 512 + tid;
        int k  = ti & 127;
        int dq = ti >> 7;             // 0..31
        bf16x4 pk;
#pragma unroll
        for (int r = 0; r < 4; ++r)
            pk[r] = (__bf16)W2[(size_t)(4 * dq + r) * MM + k];
        *(bf16x4*)(ldsW2T + k * 136 + dq * 4) = pk;
    }
    if (tid < 128)      ldsB1[tid] = b1[tid];
    else if (tid < 256) ldsB2[tid - 128] = b2[tid - 128];

    // Xa(t0) -> LDS (waits xpre), then issue Xa(t0+1) loads
#pragma unroll
    for (int p = 0; p < 4; ++p) {
        bf16x4 pk;
        pk[0] = (__bf16)xpre[p][0]; pk[1] = (__bf16)xpre[p][1];
        pk[2] = (__bf16)xpre[p][2]; pk[3] = (__bf16)xpre[p][3];
        *(bf16x4*)(ldsXa + (p * 32 + xrow) * 72 + xc) = pk;
    }
#pragma unroll
    for (int p = 0; p < 4; ++p)
        xpre[p] = *(const f32x4*)(xa + ((size_t)(p * 32 + xrow) * TT + (t0 + 1)) * AA + xc);

    __syncthreads();

    f32x4 acc[8];
    for (int it = 0; it < TPB; ++it) {
        const int t = t0 + it;

        // ---- phase 1: D[d][m] = sum_a W1T[d][a]*Xa[m][a]; epi: +b1, relu -> H[m][d] ----
        {
            bf16x8 a1[2];
#pragma unroll
            for (int ks = 0; ks < 2; ++ks)
                a1[ks] = *(const bf16x8*)(ldsW1T + (wv * 16 + n) * 72 + ks * 32 + q * 8);
#pragma unroll
            for (int mt = 0; mt < 8; ++mt) acc[mt] = (f32x4){0.f, 0.f, 0.f, 0.f};
#pragma unroll
            for (int mt = 0; mt < 8; ++mt) {
#pragma unroll
                for (int ks = 0; ks < 2; ++ks) {
                    bf16x8 bb = *(const bf16x8*)(ldsXa + (mt * 16 + n) * 72 + ks * 32 + q * 8);
                    acc[mt] = __builtin_amdgcn_mfma_f32_16x16x32_bf16(a1[ks], bb, acc[mt], 0, 0, 0);
                }
            }
            int dbase = wv * 16 + q * 4;
            float bv0 = ldsB1[dbase + 0], bv1 = ldsB1[dbase + 1];
            float bv2 = ldsB1[dbase + 2], bv3 = ldsB1[dbase + 3];
#pragma unroll
            for (int mt = 0; mt < 8; ++mt) {
                int m = mt * 16 + n;
                bf16x4 pk;
                pk[0] = (__bf16)fmaxf(acc[mt][0] + bv0, 0.f);
                pk[1] = (__bf16)fmaxf(acc[mt][1] + bv1, 0.f);
                pk[2] = (__bf16)fmaxf(acc[mt][2] + bv2, 0.f);
                pk[3] = (__bf16)fmaxf(acc[mt][3] + bv3, 0.f);
                *(bf16x4*)(ldsH + m * 136 + dbase) = pk;
            }
        }
        __syncthreads();   // barrier 1: H ready; Xa dead

        // ---- window: restage Xa(t+1) into the dead buffer (readers of iter t all past bar1) ----
        if (it < TPB - 1) {
#pragma unroll
            for (int p = 0; p < 4; ++p) {
                bf16x4 pk;
                pk[0] = (__bf16)xpre[p][0]; pk[1] = (__bf16)xpre[p][1];
                pk[2] = (__bf16)xpre[p][2]; pk[3] = (__bf16)xpre[p][3];
                *(bf16x4*)(ldsXa + (p * 32 + xrow) * 72 + xc) = pk;
            }
        }

        // ---- phase 2: D[j][k] = sum_d H[j][d]*W2T[k][d]; epi: +b2 -> ST[k][j] ----
        {
            bf16x8 a2[4];
#pragma unroll
            for (int ks = 0; ks < 4; ++ks)
                a2[ks] = *(const bf16x8*)(ldsH + (wv * 16 + n) * 136 + ks * 32 + q * 8);
#pragma unroll
            for (int kt = 0; kt < 8; ++kt) acc[kt] = (f32x4){0.f, 0.f, 0.f, 0.f};
#pragma unroll
            for (int kt = 0; kt < 8; ++kt) {
#pragma unroll
                for (int ks = 0; ks < 4; ++ks) {
                    bf16x8 bb = *(const bf16x8*)(ldsW2T + (kt * 16 + n) * 136 + ks * 32 + q * 8);
                    acc[kt] = __builtin_amdgcn_mfma_f32_16x16x32_bf16(a2[ks], bb, acc[kt], 0, 0, 0);
                }
            }
            int jbase = wv * 16 + q * 4;
#pragma unroll
            for (int kt = 0; kt < 8; ++kt) {
                int k = kt * 16 + n;
                float bv = ldsB2[k];
                bf16x4 pk;
                pk[0] = (__bf16)(acc[kt][0] + bv);
                pk[1] = (__bf16)(acc[kt][1] + bv);
                pk[2] = (__bf16)(acc[kt][2] + bv);
                pk[3] = (__bf16)(acc[kt][3] + bv);
                *(bf16x4*)(ldsS + k * 136 + jbase) = pk;
            }
        }
        __syncthreads();   // barrier 2: S ready
        // (no barrier after phase 3: ph2(it+1)'s S-writes are fenced by barrier1(it+1),
        //  which no wave passes before ALL waves finished ph3(it).)

        // ---- phase 3: out[i][k] = sum_j A[i][j]*ST[k][j]; prefetch A(t+1), Xa(t+2) ----
        {
            bf16x8 a3[4];
#pragma unroll
            for (int ks = 0; ks < 4; ++ks) {
                f32x4 lo = apre[2 * ks], hi = apre[2 * ks + 1];
                bf16x8 v;
                v[0] = (__bf16)lo[0]; v[1] = (__bf16)lo[1]; v[2] = (__bf16)lo[2]; v[3] = (__bf16)lo[3];
                v[4] = (__bf16)hi[0]; v[5] = (__bf16)hi[1]; v[6] = (__bf16)hi[2]; v[7] = (__bf16)hi[3];
                a3[ks] = v;
            }
            if (it < TPB - 1) {   // issue A(t+1); apre regs dead after conversion above
                const float* arow = abase + ((size_t)(t + 1) * MM + wv * 16 + n) * MM;
#pragma unroll
                for (int ks = 0; ks < 4; ++ks) {
                    apre[2 * ks]     = *(const f32x4*)(arow + ks * 32 + q * 8);
                    apre[2 * ks + 1] = *(const f32x4*)(arow + ks * 32 + q * 8 + 4);
                }
            }
            if (it < TPB - 2) {   // issue Xa(t+2); xpre regs dead after window write above
#pragma unroll
                for (int p = 0; p < 4; ++p)
                    xpre[p] = *(const f32x4*)(xa + ((size_t)(p * 32 + xrow) * TT + (t + 2)) * AA + xc);
            }
#pragma unroll
            for (int kt = 0; kt < 8; ++kt) acc[kt] = (f32x4){0.f, 0.f, 0.f, 0.f};
#pragma unroll
            for (int kt = 0; kt < 8; ++kt) {
#pragma unroll
                for (int ks = 0; ks < 4; ++ks) {
                    bf16x8 bb = *(const bf16x8*)(ldsS + (kt * 16 + n) * 136 + ks * 32 + q * 8);
                    acc[kt] = __builtin_amdgcn_mfma_f32_16x16x32_bf16(a3[ks], bb, acc[kt], 0, 0, 0);
                }
            }
            float* orow = out + (size_t)t * MM * MM;
            int ibase = wv * 16 + q * 4;
#pragma unroll
            for (int kt = 0; kt < 8; ++kt) {
                int k = kt * 16 + n;
#pragma unroll
                for (int r = 0; r < 4; ++r)
                    orow[(size_t)(ibase + r) * MM + k] = acc[kt][r];
            }
        }
    }
}

extern "C" void kernel_launch(void* const* d_in, const int* in_sizes, int n_in,
                              void* d_out, int out_size, void* d_ws, size_t ws_size,
                              hipStream_t stream) {
    const float* xm = (const float*)d_in[0];
    const float* xa = (const float*)d_in[1];
    const float* W1 = (const float*)d_in[2];
    const float* b1 = (const float*)d_in[3];
    const float* W2 = (const float*)d_in[4];
    const float* b2 = (const float*)d_in[5];
    float* out = (float*)d_out;
    slam_fused2<<<dim3(TT / TPB), dim3(512), 0, stream>>>(xm, xa, W1, b1, W2, b2, out);
}

// Round 4
// 359.448 us; speedup vs baseline: 1.0230x; 1.0041x over previous
//
#include <hip/hip_runtime.h>

// SLAM layer, fused: h = relu(x_aux@W1+b1); S = h@W2+b2; out[t] = x_main[-1,t,0] @ S[:,t,:]
// N,T,M,A,D = 4,1024,128,64,128.
// v4 = v2 restored (v3's 1024-thread variant core-dumped; v2 is the proven-best at 360.9 us).
//     TPB=4 t-values per block (grid 256 = 1 block/CU, single round).
//     W1T/W2T staged ONCE per block with coalesced reads + b64 LDS writes.
//     2 barriers per t-iter; Xa/A register-prefetched one iter ahead.

#define TT 1024
#define MM 128
#define AA 64
#define DD 128
#define TPB 4

typedef float  f32x4  __attribute__((ext_vector_type(4)));
typedef __bf16 bf16x8 __attribute__((ext_vector_type(8)));
typedef __bf16 bf16x4 __attribute__((ext_vector_type(4)));

// LDS row strides (elements): 64-wide mats padded to 72 (144 B), 128-wide padded to 136 (272 B).
// Frag reads are 16 B aligned; 16-lane row-step reads are 2-way max (verified layout).

__global__ __launch_bounds__(512, 1)
void slam_fused4(const float* __restrict__ xm, const float* __restrict__ xa,
                 const float* __restrict__ W1, const float* __restrict__ b1,
                 const float* __restrict__ W2, const float* __restrict__ b2,
                 float* __restrict__ out)
{
    __shared__ __bf16 ldsW1T[ 9216];   // [d=128][72]  (a<64 valid)  - resident all iters
    __shared__ __bf16 ldsXa [ 9216];   // [m=128][72]  (a<64 valid)  - rewritten per iter
    __shared__ __bf16 ldsW2T[17408];   // [k=128][136] (d<128 valid) - resident all iters
    __shared__ __bf16 ldsH  [17408];   // [m=128][136]
    __shared__ __bf16 ldsS  [17408];   // ST[k=128][136] (col j)
    __shared__ float  ldsB1[128];
    __shared__ float  ldsB2[128];
    // total 142336 B -> 1 block/CU

    const int t0   = blockIdx.x * TPB;
    const int tid  = threadIdx.x;
    const int lane = tid & 63;
    const int wv   = tid >> 6;       // 0..7
    const int n    = lane & 15;      // MFMA col index within tile
    const int q    = lane >> 4;      // quad 0..3

    // ---- prologue: issue A(t0) and Xa(t0) global loads ----
    const float* abase = xm + (size_t)3 * TT * MM * MM;
    f32x4 apre[8];
    {
        const float* arow = abase + ((size_t)t0 * MM + wv * 16 + n) * MM;
#pragma unroll
        for (int ks = 0; ks < 4; ++ks) {
            apre[2 * ks]     = *(const f32x4*)(arow + ks * 32 + q * 8);
            apre[2 * ks + 1] = *(const f32x4*)(arow + ks * 32 + q * 8 + 4);
        }
    }
    const int xrow = tid >> 4;        // 0..31 (row base within 32-row group)
    const int xc   = (tid & 15) * 4;  // a-column (x4)
    f32x4 xpre[4];
#pragma unroll
    for (int p = 0; p < 4; ++p)
        xpre[p] = *(const f32x4*)(xa + ((size_t)(p * 32 + xrow) * TT + t0) * AA + xc);

    // ---- stage W1T: [d][a] <- W1[a][d]; lanes step d (coalesced 4B reads, b64 writes, <=4-way) ----
#pragma unroll
    for (int p = 0; p < 4; ++p) {
        int ti = p * 512 + tid;
        int d  = ti & 127;
        int aq = ti >> 7;             // 0..15
        bf16x4 pk;
#pragma unroll
        for (int r = 0; r < 4; ++r)
            pk[r] = (__bf16)W1[(size_t)(4 * aq + r) * DD + d];
        *(bf16x4*)(ldsW1T + d * 72 + aq * 4) = pk;
    }
    // ---- stage W2T: [k][d] <- W2[d][k]; lanes step k ----
#pragma unroll
    for (int p = 0; p < 8; ++p) {
        int ti = p * 512 + tid;
        int k  = ti & 127;
        int dq = ti >> 7;             // 0..31
        bf16x4 pk;
#pragma unroll
        for (int r = 0; r < 4; ++r)
            pk[r] = (__bf16)W2[(size_t)(4 * dq + r) * MM + k];
        *(bf16x4*)(ldsW2T + k * 136 + dq * 4) = pk;
    }
    if (tid < 128)      ldsB1[tid] = b1[tid];
    else if (tid < 256) ldsB2[tid - 128] = b2[tid - 128];

    // Xa(t0) -> LDS (waits xpre), then issue Xa(t0+1) loads
#pragma unroll
    for (int p = 0; p < 4; ++p) {
        bf16x4 pk;
        pk[0] = (__bf16)xpre[p][0]; pk[1] = (__bf16)xpre[p][1];
        pk[2] = (__bf16)xpre[p][2]; pk[3] = (__bf16)xpre[p][3];
        *(bf16x4*)(ldsXa + (p * 32 + xrow) * 72 + xc) = pk;
    }
#pragma unroll
    for (int p = 0; p < 4; ++p)
        xpre[p] = *(const f32x4*)(xa + ((size_t)(p * 32 + xrow) * TT + (t0 + 1)) * AA + xc);

    __syncthreads();

    f32x4 acc[8];
    for (int it = 0; it < TPB; ++it) {
        const int t = t0 + it;

        // ---- phase 1: D[d][m] = sum_a W1T[d][a]*Xa[m][a]; epi: +b1, relu -> H[m][d] ----
        {
            bf16x8 a1[2];
#pragma unroll
            for (int ks = 0; ks < 2; ++ks)
                a1[ks] = *(const bf16x8*)(ldsW1T + (wv * 16 + n) * 72 + ks * 32 + q * 8);
#pragma unroll
            for (int mt = 0; mt < 8; ++mt) acc[mt] = (f32x4){0.f, 0.f, 0.f, 0.f};
#pragma unroll
            for (int mt = 0; mt < 8; ++mt) {
#pragma unroll
                for (int ks = 0; ks < 2; ++ks) {
                    bf16x8 bb = *(const bf16x8*)(ldsXa + (mt * 16 + n) * 72 + ks * 32 + q * 8);
                    acc[mt] = __builtin_amdgcn_mfma_f32_16x16x32_bf16(a1[ks], bb, acc[mt], 0, 0, 0);
                }
            }
            int dbase = wv * 16 + q * 4;
            float bv0 = ldsB1[dbase + 0], bv1 = ldsB1[dbase + 1];
            float bv2 = ldsB1[dbase + 2], bv3 = ldsB1[dbase + 3];
#pragma unroll
            for (int mt = 0; mt < 8; ++mt) {
                int m = mt * 16 + n;
                bf16x4 pk;
                pk[0] = (__bf16)fmaxf(acc[mt][0] + bv0, 0.f);
                pk[1] = (__bf16)fmaxf(acc[mt][1] + bv1, 0.f);
                pk[2] = (__bf16)fmaxf(acc[mt][2] + bv2, 0.f);
                pk[3] = (__bf16)fmaxf(acc[mt][3] + bv3, 0.f);
                *(bf16x4*)(ldsH + m * 136 + dbase) = pk;
            }
        }
        __syncthreads();   // barrier 1: H ready; Xa dead

        // ---- window: restage Xa(t+1) into the dead buffer (readers of iter t all past bar1) ----
        if (it < TPB - 1) {
#pragma unroll
            for (int p = 0; p < 4; ++p) {
                bf16x4 pk;
                pk[0] = (__bf16)xpre[p][0]; pk[1] = (__bf16)xpre[p][1];
                pk[2] = (__bf16)xpre[p][2]; pk[3] = (__bf16)xpre[p][3];
                *(bf16x4*)(ldsXa + (p * 32 + xrow) * 72 + xc) = pk;
            }
        }

        // ---- phase 2: D[j][k] = sum_d H[j][d]*W2T[k][d]; epi: +b2 -> ST[k][j] ----
        {
            bf16x8 a2[4];
#pragma unroll
            for (int ks = 0; ks < 4; ++ks)
                a2[ks] = *(const bf16x8*)(ldsH + (wv * 16 + n) * 136 + ks * 32 + q * 8);
#pragma unroll
            for (int kt = 0; kt < 8; ++kt) acc[kt] = (f32x4){0.f, 0.f, 0.f, 0.f};
#pragma unroll
            for (int kt = 0; kt < 8; ++kt) {
#pragma unroll
                for (int ks = 0; ks < 4; ++ks) {
                    bf16x8 bb = *(const bf16x8*)(ldsW2T + (kt * 16 + n) * 136 + ks * 32 + q * 8);
                    acc[kt] = __builtin_amdgcn_mfma_f32_16x16x32_bf16(a2[ks], bb, acc[kt], 0, 0, 0);
                }
            }
            int jbase = wv * 16 + q * 4;
#pragma unroll
            for (int kt = 0; kt < 8; ++kt) {
                int k = kt * 16 + n;
                float bv = ldsB2[k];
                bf16x4 pk;
                pk[0] = (__bf16)(acc[kt][0] + bv);
                pk[1] = (__bf16)(acc[kt][1] + bv);
                pk[2] = (__bf16)(acc[kt][2] + bv);
                pk[3] = (__bf16)(acc[kt][3] + bv);
                *(bf16x4*)(ldsS + k * 136 + jbase) = pk;
            }
        }
        __syncthreads();   // barrier 2: S ready
        // (no barrier after phase 3: ph2(it+1)'s S-writes are fenced by barrier1(it+1),
        //  which no wave passes before ALL waves finished ph3(it).)

        // ---- phase 3: out[i][k] = sum_j A[i][j]*ST[k][j]; prefetch A(t+1), Xa(t+2) ----
        {
            bf16x8 a3[4];
#pragma unroll
            for (int ks = 0; ks < 4; ++ks) {
                f32x4 lo = apre[2 * ks], hi = apre[2 * ks + 1];
                bf16x8 v;
                v[0] = (__bf16)lo[0]; v[1] = (__bf16)lo[1]; v[2] = (__bf16)lo[2]; v[3] = (__bf16)lo[3];
                v[4] = (__bf16)hi[0]; v[5] = (__bf16)hi[1]; v[6] = (__bf16)hi[2]; v[7] = (__bf16)hi[3];
                a3[ks] = v;
            }
            if (it < TPB - 1) {   // issue A(t+1); apre regs dead after conversion above
                const float* arow = abase + ((size_t)(t + 1) * MM + wv * 16 + n) * MM;
#pragma unroll
                for (int ks = 0; ks < 4; ++ks) {
                    apre[2 * ks]     = *(const f32x4*)(arow + ks * 32 + q * 8);
                    apre[2 * ks + 1] = *(const f32x4*)(arow + ks * 32 + q * 8 + 4);
                }
            }
            if (it < TPB - 2) {   // issue Xa(t+2); xpre regs dead after window write above
#pragma unroll
                for (int p = 0; p < 4; ++p)
                    xpre[p] = *(const f32x4*)(xa + ((size_t)(p * 32 + xrow) * TT + (t + 2)) * AA + xc);
            }
#pragma unroll
            for (int kt = 0; kt < 8; ++kt) acc[kt] = (f32x4){0.f, 0.f, 0.f, 0.f};
#pragma unroll
            for (int kt = 0; kt < 8; ++kt) {
#pragma unroll
                for (int ks = 0; ks < 4; ++ks) {
                    bf16x8 bb = *(const bf16x8*)(ldsS + (kt * 16 + n) * 136 + ks * 32 + q * 8);
                    acc[kt] = __builtin_amdgcn_mfma_f32_16x16x32_bf16(a3[ks], bb, acc[kt], 0, 0, 0);
                }
            }
            float* orow = out + (size_t)t * MM * MM;
            int ibase = wv * 16 + q * 4;
#pragma unroll
            for (int kt = 0; kt < 8; ++kt) {
                int k = kt * 16 + n;
#pragma unroll
                for (int r = 0; r < 4; ++r)
                    orow[(size_t)(ibase + r) * MM + k] = acc[kt][r];
            }
        }
    }
}

extern "C" void kernel_launch(void* const* d_in, const int* in_sizes, int n_in,
                              void* d_out, int out_size, void* d_ws, size_t ws_size,
                              hipStream_t stream) {
    const float* xm = (const float*)d_in[0];
    const float* xa = (const float*)d_in[1];
    const float* W1 = (const float*)d_in[2];
    const float* b1 = (const float*)d_in[3];
    const float* W2 = (const float*)d_in[4];
    const float* b2 = (const float*)d_in[5];
    float* out = (float*)d_out;
    slam_fused4<<<dim3(TT / TPB), dim3(512), 0, stream>>>(xm, xa, W1, b1, W2, b2, out);
}